// Round 7
// baseline (216.156 us; speedup 1.0000x reference)
//
#include <hip/hip_runtime.h>
#include <hip/hip_bf16.h>

#define N_NODES   100000
#define N_EDGES   1250000
#define N_GRAPHS  512
#define HIDDEN    64
#define F_IN      3
#define N_CLASSES 5

// bucket sort parameters
#define BKT_SHIFT 9
#define BKT_NODES 512                                    // nodes per bucket
#define N_BKT     ((N_NODES + BKT_NODES - 1) / BKT_NODES)  // 196
#define EBLK      256                                    // edge blocks in P1/P3
#define ECHUNK    ((N_EDGES + EBLK - 1) / EBLK)          // 4883

// bf16 helpers (RNE; inputs are finite)
__device__ __forceinline__ unsigned short f2bf(float f) {
    unsigned u = __float_as_uint(f);
    u += 0x7FFF + ((u >> 16) & 1);
    return (unsigned short)(u >> 16);
}

// ---------------------------------------------------------------------------
// P1: per-edge-block histogram over dst buckets (LDS, no global atomics)
__global__ void k_hist(const int* __restrict__ dst, int* __restrict__ hist) {
    __shared__ int h[N_BKT];
    for (int i = threadIdx.x; i < N_BKT; i += 256) h[i] = 0;
    __syncthreads();
    int e0 = blockIdx.x * ECHUNK, e1 = min(e0 + ECHUNK, N_EDGES);
    for (int e = e0 + threadIdx.x; e < e1; e += 256)
        atomicAdd(&h[dst[e] >> BKT_SHIFT], 1);
    __syncthreads();
    for (int i = threadIdx.x; i < N_BKT; i += 256)
        hist[blockIdx.x * N_BKT + i] = h[i];
}

// P2a: column scan — colscan[B][b] = sum_{B'<B} hist[B'][b]; btot[b] = total
__global__ void k_colscan(const int* __restrict__ hist, int* __restrict__ colscan,
                          int* __restrict__ btot) {
    __shared__ int s[256];
    int b = blockIdx.x;
    int v = hist[threadIdx.x * N_BKT + b];
    s[threadIdx.x] = v;
    __syncthreads();
    for (int off = 1; off < 256; off <<= 1) {
        int t = (threadIdx.x >= off) ? s[threadIdx.x - off] : 0;
        __syncthreads();
        s[threadIdx.x] += t;
        __syncthreads();
    }
    colscan[threadIdx.x * N_BKT + b] = s[threadIdx.x] - v;
    if (threadIdx.x == 255) btot[b] = s[255];
}

// P2b: exclusive scan of bucket totals -> base[0..N_BKT]
__global__ void k_bktbase(const int* __restrict__ btot, int* __restrict__ base) {
    __shared__ int s[256];
    int v = (threadIdx.x < N_BKT) ? btot[threadIdx.x] : 0;
    s[threadIdx.x] = v;
    __syncthreads();
    for (int off = 1; off < 256; off <<= 1) {
        int t = (threadIdx.x >= off) ? s[threadIdx.x - off] : 0;
        __syncthreads();
        s[threadIdx.x] += t;
        __syncthreads();
    }
    if (threadIdx.x < N_BKT) base[threadIdx.x] = s[threadIdx.x] - v;
    if (threadIdx.x == N_BKT - 1) base[N_BKT] = s[threadIdx.x];
}

// P3: scatter edges into bucket-grouped ebuf via LDS cursors.
//     packed: (src << 9) | (dst & 511)  — src < 2^17, fits an int.
__global__ void k_bktscatter(const int* __restrict__ src, const int* __restrict__ dst,
                             const int* __restrict__ base, const int* __restrict__ colscan,
                             int* __restrict__ ebuf) {
    __shared__ int cur[N_BKT];
    for (int i = threadIdx.x; i < N_BKT; i += 256)
        cur[i] = base[i] + colscan[blockIdx.x * N_BKT + i];
    __syncthreads();
    int e0 = blockIdx.x * ECHUNK, e1 = min(e0 + ECHUNK, N_EDGES);
    for (int e = e0 + threadIdx.x; e < e1; e += 256) {
        int s = src[e], d = dst[e];
        int pos = atomicAdd(&cur[d >> BKT_SHIFT], 1);
        ebuf[pos] = (s << BKT_SHIFT) | (d & (BKT_NODES - 1));
    }
}

// P4: per-bucket node fill: degree hist (LDS) -> rowptr + dis + xs4 (coalesced),
//     then LDS-cursor scatter of src into elist (contiguous region per block).
__global__ void k_bktfill(const int* __restrict__ ebuf, const int* __restrict__ base,
                          const float* __restrict__ x,
                          int* __restrict__ rowptr, float* __restrict__ dis,
                          uint2* __restrict__ xs4, int* __restrict__ elist) {
    __shared__ int cnt_l[BKT_NODES];
    __shared__ int rp_l[BKT_NODES];
    __shared__ int ps[256];
    int b = blockIdx.x, tid = threadIdx.x;
    int n0 = b * BKT_NODES;
    int e0 = base[b], e1 = base[b + 1];
    cnt_l[tid] = 0; cnt_l[tid + 256] = 0;
    __syncthreads();
    for (int e = e0 + tid; e < e1; e += 256)
        atomicAdd(&cnt_l[ebuf[e] & (BKT_NODES - 1)], 1);
    __syncthreads();
    int a = cnt_l[2 * tid], c = cnt_l[2 * tid + 1];
    int p = a + c;
    ps[tid] = p;
    __syncthreads();
    for (int off = 1; off < 256; off <<= 1) {
        int t = (tid >= off) ? ps[tid - off] : 0;
        __syncthreads();
        ps[tid] += t;
        __syncthreads();
    }
    int bs = ps[tid] - p;                 // exclusive over pairs
    rp_l[2 * tid] = bs;
    rp_l[2 * tid + 1] = bs + a;
    __syncthreads();
#pragma unroll
    for (int k = 0; k < 2; k++) {
        int i = tid + k * 256;
        int node = n0 + i;
        if (node < N_NODES) {
            rowptr[node] = e0 + rp_l[i];
            float dv = rsqrtf((float)cnt_l[i] + 1.0f);
            dis[node] = dv;
            float x0 = x[node * 3 + 0], x1 = x[node * 3 + 1], x2 = x[node * 3 + 2];
            xs4[node] = make_uint2((unsigned)f2bf(x0 * dv) |
                                   ((unsigned)f2bf(x1 * dv) << 16),
                                   (unsigned)f2bf(x2 * dv));
        }
    }
    if (b == 0 && tid == 0) rowptr[N_NODES] = N_EDGES;
    __syncthreads();
    cnt_l[tid] = rp_l[tid];               // reuse cnt_l as cursor
    cnt_l[tid + 256] = rp_l[tid + 256];
    __syncthreads();
    for (int e = e0 + tid; e < e1; e += 256) {
        int pe = ebuf[e];
        int pos = atomicAdd(&cnt_l[pe & (BKT_NODES - 1)], 1);
        elist[e0 + pos] = ((unsigned)pe) >> BKT_SHIFT;
    }
}

// ---------------------------------------------------------------------------
// 3-channel gather (bf16 source rows): aggx[n] = dis[n]*( sum_s xs[s] + xs[n] )
__global__ void k_aggx(const int* __restrict__ rp, const int* __restrict__ elist,
                       const float* __restrict__ dis, const uint2* __restrict__ xs4,
                       float* __restrict__ aggx) {
    int n = blockIdx.x * blockDim.x + threadIdx.x;
    if (n >= N_NODES) return;
    int start = rp[n], end = rp[n + 1];
    float a0 = 0.f, a1 = 0.f, a2 = 0.f;
    for (int e = start; e < end; e++) {
        int s = elist[e];
        uint2 u = xs4[s];
        a0 += __uint_as_float(u.x << 16);
        a1 += __uint_as_float(u.x & 0xFFFF0000u);
        a2 += __uint_as_float(u.y << 16);
    }
    uint2 un = xs4[n];
    float dn = dis[n];
    aggx[n * 3 + 0] = dn * (a0 + __uint_as_float(un.x << 16));
    aggx[n * 3 + 1] = dn * (a1 + __uint_as_float(un.x & 0xFFFF0000u));
    aggx[n * 3 + 2] = dn * (a2 + __uint_as_float(un.y << 16));
}

// h1 row = relu(aggx@W1 + b1) * dis, quantized: uint8[64] + f32 row-scale.
// wave per node: rowmax via xor-shuffles, shuffle-pack 4 bytes/dword,
// 16-lane coalesced 64B store.
__global__ void k_l1(const float* __restrict__ aggx, const float* __restrict__ W1,
                     const float* __restrict__ b1, const float* __restrict__ dis,
                     unsigned* __restrict__ h1q32, float* __restrict__ hscale) {
    int node = blockIdx.x * 4 + (threadIdx.x >> 6);
    int lane = threadIdx.x & 63;
    if (node >= N_NODES) return;
    float a0 = aggx[node * 3 + 0], a1 = aggx[node * 3 + 1], a2 = aggx[node * 3 + 2];
    float v = a0 * W1[lane] + a1 * W1[HIDDEN + lane] + a2 * W1[2 * HIDDEN + lane] + b1[lane];
    v = fmaxf(v, 0.0f) * dis[node];
    float m = v;
#pragma unroll
    for (int off = 1; off < 64; off <<= 1) m = fmaxf(m, __shfl_xor(m, off));
    float inv = (m > 0.0f) ? 255.0f / m : 0.0f;
    int q = (int)(v * inv + 0.5f);        // 0..255
    int base = lane & ~3;
    unsigned packed = (unsigned)__shfl(q, base) |
                      ((unsigned)__shfl(q, base + 1) << 8) |
                      ((unsigned)__shfl(q, base + 2) << 16) |
                      ((unsigned)__shfl(q, base + 3) << 24);
    unsigned mine = __shfl(packed, lane * 4);   // lanes 0..15 get dwords 0..15
    if (lane < 16) h1q32[node * 16 + lane] = mine;
    if (lane == 0) hscale[node] = m * (1.0f / 255.0f);
}

// 64-channel gather (uint8 rows, 64B = 1 line/edge):
// B[n] = dis[n] * ( sum_s q[s]*scale[s] + q[n]*scale[n] )
// lane = (edge-group eg 0..7, byte-octet ch 0..7); 8 edges per wave-step.
__global__ void k_gather64(const int* __restrict__ rp, const int* __restrict__ elist,
                           const float* __restrict__ dis,
                           const unsigned char* __restrict__ Hq,
                           const float* __restrict__ Hs,
                           float* __restrict__ OUT) {
    int node = blockIdx.x * 4 + (threadIdx.x >> 6);
    int lane = threadIdx.x & 63;
    if (node >= N_NODES) return;
    int start = rp[node], deg = rp[node + 1] - start;
    int eg = lane >> 3;      // which of 8 concurrent edges
    int ch = lane & 7;       // which byte-octet of the row
    float acc[8] = {0.f, 0.f, 0.f, 0.f, 0.f, 0.f, 0.f, 0.f};
    for (int base = 0; base < deg; base += 64) {
        int m = min(64, deg - base);
        int eid = (lane < m) ? elist[start + base + lane] : 0;
        int k = 0;
        for (; k + 8 <= m; k += 8) {
            int s = __shfl(eid, k + eg);
            uint2 u = *(const uint2*)(Hq + ((size_t)s << 6) + (ch << 3));
            float sc = Hs[s];
#pragma unroll
            for (int i = 0; i < 4; i++)
                acc[i] = fmaf((float)((u.x >> (8 * i)) & 0xFF), sc, acc[i]);
#pragma unroll
            for (int i = 0; i < 4; i++)
                acc[4 + i] = fmaf((float)((u.y >> (8 * i)) & 0xFF), sc, acc[4 + i]);
        }
        for (; k < m; k++) {             // <=7 leftover edges
            int s = __shfl(eid, k);
            if (eg == 0) {
                uint2 u = *(const uint2*)(Hq + ((size_t)s << 6) + (ch << 3));
                float sc = Hs[s];
#pragma unroll
                for (int i = 0; i < 4; i++)
                    acc[i] = fmaf((float)((u.x >> (8 * i)) & 0xFF), sc, acc[i]);
#pragma unroll
                for (int i = 0; i < 4; i++)
                    acc[4 + i] = fmaf((float)((u.y >> (8 * i)) & 0xFF), sc, acc[4 + i]);
            }
        }
    }
#pragma unroll
    for (int i = 0; i < 8; i++) {
        acc[i] += __shfl_xor(acc[i], 8);
        acc[i] += __shfl_xor(acc[i], 16);
        acc[i] += __shfl_xor(acc[i], 32);
    }
    if (lane < 8) {                       // eg==0 lanes hold octet `lane`
        float dn = dis[node];
        uint2 u = *(const uint2*)(Hq + ((size_t)node << 6) + (lane << 3));
        float sc = Hs[node];
        float o[8];
#pragma unroll
        for (int i = 0; i < 4; i++)
            o[i] = dn * fmaf((float)((u.x >> (8 * i)) & 0xFF), sc, acc[i]);
#pragma unroll
        for (int i = 0; i < 4; i++)
            o[4 + i] = dn * fmaf((float)((u.y >> (8 * i)) & 0xFF), sc, acc[4 + i]);
        float* op = OUT + (size_t)node * HIDDEN + lane * 8;
        *(float4*)(op)     = make_float4(o[0], o[1], o[2], o[3]);
        *(float4*)(op + 4) = make_float4(o[4], o[5], o[6], o[7]);
    }
}

// ---------------------------------------------------------------------------
// merged tiny precomputes: block 0 folds the head (Wc = W2@Wl, bc = b2@Wl+bl);
// blocks >=1 fill graph boundaries gstart from the sorted batch vector.
__global__ void k_misc(const float* __restrict__ W2, const float* __restrict__ Wl,
                       const float* __restrict__ b2, const float* __restrict__ bl,
                       const int* __restrict__ batch,
                       float* __restrict__ Wc, float* __restrict__ bc,
                       int* __restrict__ gstart) {
    if (blockIdx.x == 0) {
        for (int t = threadIdx.x; t < HIDDEN * N_CLASSES + N_CLASSES; t += 256) {
            if (t < HIDDEN * N_CLASSES) {
                int k = t / N_CLASSES, c = t % N_CLASSES;
                float acc = 0.0f;
#pragma unroll
                for (int j = 0; j < HIDDEN; j++)
                    acc = fmaf(W2[k * HIDDEN + j], Wl[j * N_CLASSES + c], acc);
                Wc[t] = acc;
            } else {
                int c = t - HIDDEN * N_CLASSES;
                float acc = bl[c];
#pragma unroll
                for (int j = 0; j < HIDDEN; j++)
                    acc = fmaf(b2[j], Wl[j * N_CLASSES + c], acc);
                bc[c] = acc;
            }
        }
        return;
    }
    int n = (blockIdx.x - 1) * 256 + threadIdx.x;
    if (n >= N_NODES) return;
    if (n == 0) {
        for (int g = 0; g <= batch[0]; g++) gstart[g] = 0;
    } else {
        int b0 = batch[n - 1], b1 = batch[n];
        for (int g = b0 + 1; g <= b1; g++) gstart[g] = n;
    }
    if (n == N_NODES - 1) {
        for (int g = batch[n] + 1; g <= N_GRAPHS; g++) gstart[g] = N_NODES;
    }
}

// fused pool+head: one block (8 waves) per graph; LDS-reduce,
// then out[g,c] = (gsum @ Wc[:,c]) / max(cnt,1) + bc[c]
__global__ void k_poolhead(const float* __restrict__ H2, const int* __restrict__ gstart,
                           const float* __restrict__ Wc, const float* __restrict__ bc,
                           float* __restrict__ out) {
    __shared__ float part[8][HIDDEN];
    __shared__ float gl[HIDDEN];
    int g = blockIdx.x;
    int s = gstart[g], e = gstart[g + 1];
    int c = threadIdx.x & 63, w = threadIdx.x >> 6;
    float acc = 0.0f;
    for (int n = s + w; n < e; n += 8)
        acc += H2[(size_t)n * HIDDEN + c];
    part[w][c] = acc;
    __syncthreads();
    if (threadIdx.x < HIDDEN) {
        float t = 0.0f;
#pragma unroll
        for (int k = 0; k < 8; k++) t += part[k][threadIdx.x];
        gl[threadIdx.x] = t;
    }
    __syncthreads();
    if (threadIdx.x < N_CLASSES) {
        int cc = threadIdx.x;
        float cntf = fmaxf((float)(e - s), 1.0f);
        float dot = 0.0f;
#pragma unroll
        for (int k = 0; k < HIDDEN; k++)
            dot = fmaf(gl[k], Wc[k * N_CLASSES + cc], dot);
        out[g * N_CLASSES + cc] = dot / cntf + bc[cc];
    }
}

// ---------------------------------------------------------------------------
extern "C" void kernel_launch(void* const* d_in, const int* in_sizes, int n_in,
                              void* d_out, int out_size, void* d_ws, size_t ws_size,
                              hipStream_t stream) {
    const float* x     = (const float*)d_in[0];
    const int*   ei    = (const int*)  d_in[1];   // [2, N_EDGES] flat: src then dst
    const int*   batch = (const int*)  d_in[2];
    const float* W1    = (const float*)d_in[3];
    const float* b1    = (const float*)d_in[4];
    const float* W2    = (const float*)d_in[5];
    const float* b2    = (const float*)d_in[6];
    const float* Wl    = (const float*)d_in[7];
    const float* bl    = (const float*)d_in[8];
    float* out = (float*)d_out;

    const int* src = ei;
    const int* dst = ei + N_EDGES;

    // workspace layout (4B words; segments padded so h1q is 8B- and B 16B-aligned)
    uint2* xs4     = (uint2*)d_ws;                       // N uint2 (2N words)
    int*   ebuf    = (int*)(xs4 + N_NODES);              // E (packed src|dstlocal)
    int*   elist   = ebuf + N_EDGES;                     // E
    int*   hist    = elist + N_EDGES;                    // EBLK*N_BKT
    int*   colscan = hist + EBLK * N_BKT;                // EBLK*N_BKT
    int*   btot    = colscan + EBLK * N_BKT;             // N_BKT (196)
    int*   base    = btot + N_BKT;                       // N_BKT+1, reserve 200
    int*   rowptr  = base + 200;                         // N+1, reserve 100004
    float* dis     = (float*)(rowptr + 100004);          // N
    float* hscale  = dis + N_NODES;                      // N
    float* aggx    = hscale + N_NODES;                   // 3N
    unsigned* h1q32 = (unsigned*)(aggx + (size_t)N_NODES * F_IN); // 16N words (uint8 rows)
    float* B       = (float*)(h1q32 + (size_t)N_NODES * 16);      // 64N f32
    int*   gstart  = (int*)(B + (size_t)N_NODES * HIDDEN);        // N_GRAPHS+1
    float* Wc      = (float*)(gstart + N_GRAPHS + 1);    // 64*5
    float* bc      = Wc + HIDDEN * N_CLASSES;            // 5

    const int BS = 256;
    const int g_nodes  = (N_NODES + BS - 1) / BS;
    const int g_wave4  = (N_NODES + 3) / 4;              // 4 waves-per-node kernels

    // CSR build: two-level counting sort, no global atomics
    k_hist<<<EBLK, 256, 0, stream>>>(dst, hist);
    k_colscan<<<N_BKT, 256, 0, stream>>>(hist, colscan, btot);
    k_bktbase<<<1, 256, 0, stream>>>(btot, base);
    k_bktscatter<<<EBLK, 256, 0, stream>>>(src, dst, base, colscan, ebuf);
    k_bktfill<<<N_BKT, 256, 0, stream>>>(ebuf, base, x, rowptr, dis, xs4, elist);

    // tiny precomputes (head fold + graph boundaries)
    k_misc<<<g_nodes + 1, 256, 0, stream>>>(W2, Wl, b2, bl, batch, Wc, bc, gstart);

    // layer 1 in input space (bf16 xs rows -> f32 aggx -> uint8 h1 rows)
    k_aggx<<<g_nodes, BS, 0, stream>>>(rowptr, elist, dis, xs4, aggx);
    k_l1<<<g_wave4, BS, 0, stream>>>(aggx, W1, b1, dis, h1q32, hscale);

    // layer 2 aggregation (uint8 rows; W2 folded into head)
    k_gather64<<<g_wave4, BS, 0, stream>>>(rowptr, elist, dis,
                                           (const unsigned char*)h1q32, hscale, B);

    // fused pool + head
    k_poolhead<<<N_GRAPHS, 512, 0, stream>>>(B, gstart, Wc, bc, out);
}

// Round 8
// 202.650 us; speedup vs baseline: 1.0666x; 1.0666x over previous
//
#include <hip/hip_runtime.h>
#include <hip/hip_bf16.h>

#define N_NODES   100000
#define N_EDGES   1250000
#define N_GRAPHS  512
#define HIDDEN    64
#define F_IN      3
#define N_CLASSES 5

// bucket sort parameters
#define BKT_SHIFT 9
#define BKT_NODES 512                                    // nodes per bucket
#define N_BKT     ((N_NODES + BKT_NODES - 1) / BKT_NODES)  // 196
#define EBLK      256                                    // edge blocks in P1/P3
#define ECHUNK    ((N_EDGES + EBLK - 1) / EBLK)          // 4883

// bf16 helpers (RNE; inputs are finite)
__device__ __forceinline__ unsigned short f2bf(float f) {
    unsigned u = __float_as_uint(f);
    u += 0x7FFF + ((u >> 16) & 1);
    return (unsigned short)(u >> 16);
}

// ---------------------------------------------------------------------------
// P1: per-edge-block histogram over dst buckets (LDS, no global atomics)
__global__ void k_hist(const int* __restrict__ dst, int* __restrict__ hist) {
    __shared__ int h[N_BKT];
    for (int i = threadIdx.x; i < N_BKT; i += 256) h[i] = 0;
    __syncthreads();
    int e0 = blockIdx.x * ECHUNK, e1 = min(e0 + ECHUNK, N_EDGES);
    for (int e = e0 + threadIdx.x; e < e1; e += 256)
        atomicAdd(&h[dst[e] >> BKT_SHIFT], 1);
    __syncthreads();
    for (int i = threadIdx.x; i < N_BKT; i += 256)
        hist[blockIdx.x * N_BKT + i] = h[i];
}

// P2a: column scan — colscan[B][b] = sum_{B'<B} hist[B'][b]; btot[b] = total
__global__ void k_colscan(const int* __restrict__ hist, int* __restrict__ colscan,
                          int* __restrict__ btot) {
    __shared__ int s[256];
    int b = blockIdx.x;
    int v = hist[threadIdx.x * N_BKT + b];
    s[threadIdx.x] = v;
    __syncthreads();
    for (int off = 1; off < 256; off <<= 1) {
        int t = (threadIdx.x >= off) ? s[threadIdx.x - off] : 0;
        __syncthreads();
        s[threadIdx.x] += t;
        __syncthreads();
    }
    colscan[threadIdx.x * N_BKT + b] = s[threadIdx.x] - v;
    if (threadIdx.x == 255) btot[b] = s[255];
}

// P2b: exclusive scan of bucket totals -> base[0..N_BKT]
__global__ void k_bktbase(const int* __restrict__ btot, int* __restrict__ base) {
    __shared__ int s[256];
    int v = (threadIdx.x < N_BKT) ? btot[threadIdx.x] : 0;
    s[threadIdx.x] = v;
    __syncthreads();
    for (int off = 1; off < 256; off <<= 1) {
        int t = (threadIdx.x >= off) ? s[threadIdx.x - off] : 0;
        __syncthreads();
        s[threadIdx.x] += t;
        __syncthreads();
    }
    if (threadIdx.x < N_BKT) base[threadIdx.x] = s[threadIdx.x] - v;
    if (threadIdx.x == N_BKT - 1) base[N_BKT] = s[threadIdx.x];
}

// P3: scatter edges into bucket-grouped ebuf via LDS cursors.
//     packed: (src << 9) | (dst & 511)  — src < 2^17, fits an int.
__global__ void k_bktscatter(const int* __restrict__ src, const int* __restrict__ dst,
                             const int* __restrict__ base, const int* __restrict__ colscan,
                             int* __restrict__ ebuf) {
    __shared__ int cur[N_BKT];
    for (int i = threadIdx.x; i < N_BKT; i += 256)
        cur[i] = base[i] + colscan[blockIdx.x * N_BKT + i];
    __syncthreads();
    int e0 = blockIdx.x * ECHUNK, e1 = min(e0 + ECHUNK, N_EDGES);
    for (int e = e0 + threadIdx.x; e < e1; e += 256) {
        int s = src[e], d = dst[e];
        int pos = atomicAdd(&cur[d >> BKT_SHIFT], 1);
        ebuf[pos] = (s << BKT_SHIFT) | (d & (BKT_NODES - 1));
    }
}

// P4: per-bucket node fill: degree hist (LDS) -> rowptr + dis + xs4 (coalesced),
//     then LDS-cursor scatter of src into elist (contiguous region per block).
__global__ void k_bktfill(const int* __restrict__ ebuf, const int* __restrict__ base,
                          const float* __restrict__ x,
                          int* __restrict__ rowptr, float* __restrict__ dis,
                          uint2* __restrict__ xs4, int* __restrict__ elist) {
    __shared__ int cnt_l[BKT_NODES];
    __shared__ int rp_l[BKT_NODES];
    __shared__ int ps[256];
    int b = blockIdx.x, tid = threadIdx.x;
    int n0 = b * BKT_NODES;
    int e0 = base[b], e1 = base[b + 1];
    cnt_l[tid] = 0; cnt_l[tid + 256] = 0;
    __syncthreads();
    for (int e = e0 + tid; e < e1; e += 256)
        atomicAdd(&cnt_l[ebuf[e] & (BKT_NODES - 1)], 1);
    __syncthreads();
    int a = cnt_l[2 * tid], c = cnt_l[2 * tid + 1];
    int p = a + c;
    ps[tid] = p;
    __syncthreads();
    for (int off = 1; off < 256; off <<= 1) {
        int t = (tid >= off) ? ps[tid - off] : 0;
        __syncthreads();
        ps[tid] += t;
        __syncthreads();
    }
    int bs = ps[tid] - p;                 // exclusive over pairs
    rp_l[2 * tid] = bs;
    rp_l[2 * tid + 1] = bs + a;
    __syncthreads();
#pragma unroll
    for (int k = 0; k < 2; k++) {
        int i = tid + k * 256;
        int node = n0 + i;
        if (node < N_NODES) {
            rowptr[node] = e0 + rp_l[i];
            float dv = rsqrtf((float)cnt_l[i] + 1.0f);
            dis[node] = dv;
            float x0 = x[node * 3 + 0], x1 = x[node * 3 + 1], x2 = x[node * 3 + 2];
            xs4[node] = make_uint2((unsigned)f2bf(x0 * dv) |
                                   ((unsigned)f2bf(x1 * dv) << 16),
                                   (unsigned)f2bf(x2 * dv));
        }
    }
    if (b == 0 && tid == 0) rowptr[N_NODES] = N_EDGES;
    __syncthreads();
    cnt_l[tid] = rp_l[tid];               // reuse cnt_l as cursor
    cnt_l[tid + 256] = rp_l[tid + 256];
    __syncthreads();
    for (int e = e0 + tid; e < e1; e += 256) {
        int pe = ebuf[e];
        int pos = atomicAdd(&cnt_l[pe & (BKT_NODES - 1)], 1);
        elist[e0 + pos] = ((unsigned)pe) >> BKT_SHIFT;
    }
}

// ---------------------------------------------------------------------------
// 3-channel gather (bf16 source rows): aggx[n] = dis[n]*( sum_s xs[s] + xs[n] )
__global__ void k_aggx(const int* __restrict__ rp, const int* __restrict__ elist,
                       const float* __restrict__ dis, const uint2* __restrict__ xs4,
                       float* __restrict__ aggx) {
    int n = blockIdx.x * blockDim.x + threadIdx.x;
    if (n >= N_NODES) return;
    int start = rp[n], end = rp[n + 1];
    float a0 = 0.f, a1 = 0.f, a2 = 0.f;
    for (int e = start; e < end; e++) {
        int s = elist[e];
        uint2 u = xs4[s];
        a0 += __uint_as_float(u.x << 16);
        a1 += __uint_as_float(u.x & 0xFFFF0000u);
        a2 += __uint_as_float(u.y << 16);
    }
    uint2 un = xs4[n];
    float dn = dis[n];
    aggx[n * 3 + 0] = dn * (a0 + __uint_as_float(un.x << 16));
    aggx[n * 3 + 1] = dn * (a1 + __uint_as_float(un.x & 0xFFFF0000u));
    aggx[n * 3 + 2] = dn * (a2 + __uint_as_float(un.y << 16));
}

// h1 row = relu(aggx@W1 + b1) * dis, quantized: uint8[64] + f32 row-scale.
// wave per node: rowmax via xor-shuffles, shuffle-pack 4 bytes/dword,
// 16-lane coalesced 64B store.
__global__ void k_l1(const float* __restrict__ aggx, const float* __restrict__ W1,
                     const float* __restrict__ b1, const float* __restrict__ dis,
                     unsigned* __restrict__ h1q32, float* __restrict__ hscale) {
    int node = blockIdx.x * 4 + (threadIdx.x >> 6);
    int lane = threadIdx.x & 63;
    if (node >= N_NODES) return;
    float a0 = aggx[node * 3 + 0], a1 = aggx[node * 3 + 1], a2 = aggx[node * 3 + 2];
    float v = a0 * W1[lane] + a1 * W1[HIDDEN + lane] + a2 * W1[2 * HIDDEN + lane] + b1[lane];
    v = fmaxf(v, 0.0f) * dis[node];
    float m = v;
#pragma unroll
    for (int off = 1; off < 64; off <<= 1) m = fmaxf(m, __shfl_xor(m, off));
    float inv = (m > 0.0f) ? 255.0f / m : 0.0f;
    int q = (int)(v * inv + 0.5f);        // 0..255
    int base = lane & ~3;
    unsigned packed = (unsigned)__shfl(q, base) |
                      ((unsigned)__shfl(q, base + 1) << 8) |
                      ((unsigned)__shfl(q, base + 2) << 16) |
                      ((unsigned)__shfl(q, base + 3) << 24);
    unsigned mine = __shfl(packed, lane * 4);   // lanes 0..15 get dwords 0..15
    if (lane < 16) h1q32[node * 16 + lane] = mine;
    if (lane == 0) hscale[node] = m * (1.0f / 255.0f);
}

// 64-channel gather (uint8 rows, 64B = 1 line/edge):
// B[n] = dis[n] * ( sum_s q[s]*scale[s] + q[n]*scale[n] )
// lane = (edge-group eg 0..3, dword ch 0..15); 4 edges per wave-step,
// tail handled by predication (sc=0), no serial leftover loop.
__global__ void k_gather64(const int* __restrict__ rp, const int* __restrict__ elist,
                           const float* __restrict__ dis,
                           const unsigned char* __restrict__ Hq,
                           const float* __restrict__ Hs,
                           float* __restrict__ OUT) {
    int node = blockIdx.x * 4 + (threadIdx.x >> 6);
    int lane = threadIdx.x & 63;
    if (node >= N_NODES) return;
    int start = rp[node], deg = rp[node + 1] - start;
    int eg = lane >> 4;      // which of 4 concurrent edges
    int ch = lane & 15;      // which dword (4 channels) of the row
    float4 acc = make_float4(0.f, 0.f, 0.f, 0.f);
    for (int base = 0; base < deg; base += 64) {
        int m = min(64, deg - base);
        int eid = (lane < m) ? elist[start + base + lane] : 0;
        for (int k = 0; k < m; k += 4) {
            int idx = k + eg;
            int s = __shfl(eid, (idx < m) ? idx : 0);
            float sc = Hs[s];
            if (idx >= m) sc = 0.0f;                       // predicated tail
            unsigned u = *(const unsigned*)(Hq + ((size_t)s << 6) + (ch << 2));
            acc.x = fmaf((float)(u & 0xFF), sc, acc.x);
            acc.y = fmaf((float)((u >> 8) & 0xFF), sc, acc.y);
            acc.z = fmaf((float)((u >> 16) & 0xFF), sc, acc.z);
            acc.w = fmaf((float)((u >> 24) & 0xFF), sc, acc.w);
        }
    }
    // reduce the 4 edge-groups (xor 16, 32)
    acc.x += __shfl_xor(acc.x, 16); acc.y += __shfl_xor(acc.y, 16);
    acc.z += __shfl_xor(acc.z, 16); acc.w += __shfl_xor(acc.w, 16);
    acc.x += __shfl_xor(acc.x, 32); acc.y += __shfl_xor(acc.y, 32);
    acc.z += __shfl_xor(acc.z, 32); acc.w += __shfl_xor(acc.w, 32);
    if (lane < 16) {
        float dn = dis[node];
        float scN = Hs[node];
        unsigned u = *(const unsigned*)(Hq + ((size_t)node << 6) + (lane << 2));
        float4 o;
        o.x = dn * fmaf((float)(u & 0xFF), scN, acc.x);
        o.y = dn * fmaf((float)((u >> 8) & 0xFF), scN, acc.y);
        o.z = dn * fmaf((float)((u >> 16) & 0xFF), scN, acc.z);
        o.w = dn * fmaf((float)((u >> 24) & 0xFF), scN, acc.w);
        *(float4*)(OUT + (size_t)node * HIDDEN + lane * 4) = o;
    }
}

// ---------------------------------------------------------------------------
// merged tiny precomputes: block 0 folds the head (Wc = W2@Wl, bc = b2@Wl+bl);
// blocks >=1 fill graph boundaries gstart from the sorted batch vector.
__global__ void k_misc(const float* __restrict__ W2, const float* __restrict__ Wl,
                       const float* __restrict__ b2, const float* __restrict__ bl,
                       const int* __restrict__ batch,
                       float* __restrict__ Wc, float* __restrict__ bc,
                       int* __restrict__ gstart) {
    if (blockIdx.x == 0) {
        for (int t = threadIdx.x; t < HIDDEN * N_CLASSES + N_CLASSES; t += 256) {
            if (t < HIDDEN * N_CLASSES) {
                int k = t / N_CLASSES, c = t % N_CLASSES;
                float acc = 0.0f;
#pragma unroll
                for (int j = 0; j < HIDDEN; j++)
                    acc = fmaf(W2[k * HIDDEN + j], Wl[j * N_CLASSES + c], acc);
                Wc[t] = acc;
            } else {
                int c = t - HIDDEN * N_CLASSES;
                float acc = bl[c];
#pragma unroll
                for (int j = 0; j < HIDDEN; j++)
                    acc = fmaf(b2[j], Wl[j * N_CLASSES + c], acc);
                bc[c] = acc;
            }
        }
        return;
    }
    int n = (blockIdx.x - 1) * 256 + threadIdx.x;
    if (n >= N_NODES) return;
    if (n == 0) {
        for (int g = 0; g <= batch[0]; g++) gstart[g] = 0;
    } else {
        int b0 = batch[n - 1], b1 = batch[n];
        for (int g = b0 + 1; g <= b1; g++) gstart[g] = n;
    }
    if (n == N_NODES - 1) {
        for (int g = batch[n] + 1; g <= N_GRAPHS; g++) gstart[g] = N_NODES;
    }
}

// fused pool+head: one block (8 waves) per graph; LDS-reduce,
// then out[g,c] = (gsum @ Wc[:,c]) / max(cnt,1) + bc[c]
__global__ void k_poolhead(const float* __restrict__ H2, const int* __restrict__ gstart,
                           const float* __restrict__ Wc, const float* __restrict__ bc,
                           float* __restrict__ out) {
    __shared__ float part[8][HIDDEN];
    __shared__ float gl[HIDDEN];
    int g = blockIdx.x;
    int s = gstart[g], e = gstart[g + 1];
    int c = threadIdx.x & 63, w = threadIdx.x >> 6;
    float acc = 0.0f;
    for (int n = s + w; n < e; n += 8)
        acc += H2[(size_t)n * HIDDEN + c];
    part[w][c] = acc;
    __syncthreads();
    if (threadIdx.x < HIDDEN) {
        float t = 0.0f;
#pragma unroll
        for (int k = 0; k < 8; k++) t += part[k][threadIdx.x];
        gl[threadIdx.x] = t;
    }
    __syncthreads();
    if (threadIdx.x < N_CLASSES) {
        int cc = threadIdx.x;
        float cntf = fmaxf((float)(e - s), 1.0f);
        float dot = 0.0f;
#pragma unroll
        for (int k = 0; k < HIDDEN; k++)
            dot = fmaf(gl[k], Wc[k * N_CLASSES + cc], dot);
        out[g * N_CLASSES + cc] = dot / cntf + bc[cc];
    }
}

// ---------------------------------------------------------------------------
extern "C" void kernel_launch(void* const* d_in, const int* in_sizes, int n_in,
                              void* d_out, int out_size, void* d_ws, size_t ws_size,
                              hipStream_t stream) {
    const float* x     = (const float*)d_in[0];
    const int*   ei    = (const int*)  d_in[1];   // [2, N_EDGES] flat: src then dst
    const int*   batch = (const int*)  d_in[2];
    const float* W1    = (const float*)d_in[3];
    const float* b1    = (const float*)d_in[4];
    const float* W2    = (const float*)d_in[5];
    const float* b2    = (const float*)d_in[6];
    const float* Wl    = (const float*)d_in[7];
    const float* bl    = (const float*)d_in[8];
    float* out = (float*)d_out;

    const int* src = ei;
    const int* dst = ei + N_EDGES;

    // workspace layout (4B words; segments padded so h1q is 8B- and B 16B-aligned)
    uint2* xs4     = (uint2*)d_ws;                       // N uint2 (2N words)
    int*   ebuf    = (int*)(xs4 + N_NODES);              // E (packed src|dstlocal)
    int*   elist   = ebuf + N_EDGES;                     // E
    int*   hist    = elist + N_EDGES;                    // EBLK*N_BKT
    int*   colscan = hist + EBLK * N_BKT;                // EBLK*N_BKT
    int*   btot    = colscan + EBLK * N_BKT;             // N_BKT (196)
    int*   base    = btot + N_BKT;                       // N_BKT+1, reserve 200
    int*   rowptr  = base + 200;                         // N+1, reserve 100004
    float* dis     = (float*)(rowptr + 100004);          // N
    float* hscale  = dis + N_NODES;                      // N
    float* aggx    = hscale + N_NODES;                   // 3N
    unsigned* h1q32 = (unsigned*)(aggx + (size_t)N_NODES * F_IN); // 16N words (uint8 rows)
    float* B       = (float*)(h1q32 + (size_t)N_NODES * 16);      // 64N f32
    int*   gstart  = (int*)(B + (size_t)N_NODES * HIDDEN);        // N_GRAPHS+1
    float* Wc      = (float*)(gstart + N_GRAPHS + 1);    // 64*5
    float* bc      = Wc + HIDDEN * N_CLASSES;            // 5

    const int BS = 256;
    const int g_nodes  = (N_NODES + BS - 1) / BS;
    const int g_wave4  = (N_NODES + 3) / 4;              // 4 waves-per-node kernels

    // CSR build: two-level counting sort, no global atomics
    k_hist<<<EBLK, 256, 0, stream>>>(dst, hist);
    k_colscan<<<N_BKT, 256, 0, stream>>>(hist, colscan, btot);
    k_bktbase<<<1, 256, 0, stream>>>(btot, base);
    k_bktscatter<<<EBLK, 256, 0, stream>>>(src, dst, base, colscan, ebuf);
    k_bktfill<<<N_BKT, 256, 0, stream>>>(ebuf, base, x, rowptr, dis, xs4, elist);

    // tiny precomputes (head fold + graph boundaries)
    k_misc<<<g_nodes + 1, 256, 0, stream>>>(W2, Wl, b2, bl, batch, Wc, bc, gstart);

    // layer 1 in input space (bf16 xs rows -> f32 aggx -> uint8 h1 rows)
    k_aggx<<<g_nodes, BS, 0, stream>>>(rowptr, elist, dis, xs4, aggx);
    k_l1<<<g_wave4, BS, 0, stream>>>(aggx, W1, b1, dis, h1q32, hscale);

    // layer 2 aggregation (uint8 rows; W2 folded into head)
    k_gather64<<<g_wave4, BS, 0, stream>>>(rowptr, elist, dis,
                                           (const unsigned char*)h1q32, hscale, B);

    // fused pool + head
    k_poolhead<<<N_GRAPHS, 512, 0, stream>>>(B, gstart, Wc, bc, out);
}